// Round 13
// baseline (447.928 us; speedup 1.0000x reference)
//
#include <hip/hip_runtime.h>

#define N_NODES 100000
#define N_EDGES 1600000
#define TOTE    (N_EDGES + N_NODES)
#define NEG     0.2f
#define NB      ((N_NODES + 255) >> 8)   // 391 buckets of 256 nodes
#define BCAP    5120                     // bucket capacity (mean 4096 + 16 sigma)
#define BINBLK  391                      // bin-pass blocks (fused kernel prefix)
#define G1H1    782                      // gemm1 half-1 tiles (bid 0..781)
#define G1H2    781                      // gemm1 half-2 tiles (bid 782..1562)
#define GEMMN   1563                     // total gemm tiles per layer

typedef __attribute__((ext_vector_type(8))) short bf16x8;
typedef __attribute__((ext_vector_type(4))) float floatx4;

// bf16 helpers (RTNE)
__device__ __forceinline__ unsigned short f2bf(float f) {
  unsigned int u = __float_as_uint(f);
  u += 0x7fffu + ((u >> 16) & 1u);
  return (unsigned short)(u >> 16);
}
__device__ __forceinline__ float bf_lo(unsigned int r) { return __uint_as_float(r << 16); }
__device__ __forceinline__ float bf_hi(unsigned int r) { return __uint_as_float(r & 0xffff0000u); }

// ====== W prep (blocks 0..15) + bucket counter / gemm-done counter zeroing (block 16) ======
__global__ __launch_bounds__(256) void k_wprep(const float* __restrict__ W1, const float* __restrict__ W2,
                                               unsigned short* __restrict__ B1hi, unsigned short* __restrict__ B1lo,
                                               unsigned short* __restrict__ B2hi, unsigned short* __restrict__ B2lo,
                                               int* __restrict__ bucketCnt, int* __restrict__ gcnt) {
  int b = blockIdx.x;                       // 0..16
  int t = threadIdx.x;
  if (b == 16) {
    for (int i = t; i < NB * 16; i += 256) bucketCnt[i] = 0;
    if (t < 4) gcnt[t] = 0;
    return;
  }
  const float* W = (b < 8) ? W1 : W2;
  unsigned short* Bh = (b < 8) ? B1hi : B2hi;
  unsigned short* Bl = (b < 8) ? B1lo : B2lo;
  int ntile = b & 7;
  int kq = t >> 6, lane = t & 63;
  int q = lane >> 4, m = lane & 15;
  int n = ntile * 16 + m;
  union { unsigned short us[8]; uint4 u4; } hi, lo;
#pragma unroll
  for (int j = 0; j < 8; ++j) {
    int k = kq * 32 + q * 8 + j;
    float w = W[(size_t)k * 128 + n];
    unsigned int u = __float_as_uint(w);
    hi.us[j] = (unsigned short)(u >> 16);                 // truncation hi
    float res = w - __uint_as_float(u & 0xffff0000u);     // exact residual
    lo.us[j] = f2bf(res);
  }
  size_t fo = ((size_t)(ntile * 4 + kq) * 64 + lane) * 8;
  *reinterpret_cast<uint4*>(Bh + fo) = hi.u4;
  *reinterpret_cast<uint4*>(Bl + fo) = lo.u4;
}

// ---- gemm epilogue: last-of-NTOT block reduces slots -> gMh (k_gmax eliminated) ----
// release: slot store + threadfence + atomicAdd; acquire: threadfence after observing count.
__device__ __forceinline__ void gmax_lastblock(
    int bid, int t, float* redS, float* redD, float* mS, float* mD,
    float* __restrict__ slotS, float* __restrict__ slotD,
    int* __restrict__ gcnt, float* __restrict__ gMh) {
  if (t == 0) {
    slotS[bid] = mS[0]; slotD[bid] = mD[0];
    __threadfence();
    int done = atomicAdd(gcnt, 1);
    mS[1] = (done == GEMMN - 1) ? 1.f : 0.f;
  }
  __syncthreads();
  if (mS[1] != 0.f) {          // block-uniform
    __threadfence();
    float ms = -1e30f, md = -1e30f;
    for (int i = t; i < GEMMN; i += 256) { ms = fmaxf(ms, slotS[i]); md = fmaxf(md, slotD[i]); }
    redS[t] = ms; redD[t] = md;
    __syncthreads();
#pragma unroll
    for (int off = 128; off > 0; off >>= 1) {
      if (t < off) { redS[t] = fmaxf(redS[t], redS[t + off]); redD[t] = fmaxf(redD[t], redD[t + off]); }
      __syncthreads();
    }
    if (t == 0) {
      float M = redS[0] + redD[0];
      gMh[0] = (M > 0.f) ? M : NEG * M;
    }
  }
}

// ---- shared gemm1 body (SPLIT=true, LDS-staged, R8/R11-proven) ----
__device__ __forceinline__ void gemm1_body(
    int bid, int t, char* sbuf, float* redS, float* redD, float* mS, float* mD,
    const float* __restrict__ x,
    const unsigned short* __restrict__ Bhi, const unsigned short* __restrict__ Blo,
    unsigned short* __restrict__ Cb,
    const float* __restrict__ avS, const float* __restrict__ avD,
    float* __restrict__ aS, float* __restrict__ aD,
    float* __restrict__ slotS, float* __restrict__ slotD,
    int* __restrict__ gcnt, float* __restrict__ gMh) {
  int w = t >> 6, lane = t & 63;
  int q = lane >> 4, m = lane & 15;
  int rbase = bid * 64;
  const char* Ab = (const char*)x;

  // async stage A tile into LDS (fp32 rows 512B -> padded 528B; 33 x 1KB chunks)
  for (int c = w; c < 33; c += 4) {
    int L = c * 1024 + lane * 16;
    int r = L / 528;
    int off = L - r * 528;
    int gr = min(rbase + r, N_NODES - 1);
    const char* src = (off < 512) ? (Ab + (size_t)gr * 512 + off) : Ab;
    __builtin_amdgcn_global_load_lds((const __attribute__((address_space(1))) void*)src,
                                     (__attribute__((address_space(3))) void*)(sbuf + c * 1024),
                                     16, 0, 0);
  }

  floatx4 acc[4][2];
#pragma unroll
  for (int mt = 0; mt < 4; ++mt)
#pragma unroll
    for (int nt = 0; nt < 2; ++nt) acc[mt][nt] = (floatx4){0.f, 0.f, 0.f, 0.f};

  __syncthreads();

#pragma unroll
  for (int k0 = 0; k0 < 4; ++k0) {
    bf16x8 Bh[2], Bl[2], Ah[4], Al[4];
#pragma unroll
    for (int nt = 0; nt < 2; ++nt) {
      int ntg = w * 2 + nt;
      size_t fo = ((size_t)(ntg * 4 + k0) * 64 + lane) * 8;
      Bh[nt] = *reinterpret_cast<const bf16x8*>(Bhi + fo);
      Bl[nt] = *reinterpret_cast<const bf16x8*>(Blo + fo);
    }
#pragma unroll
    for (int mt = 0; mt < 4; ++mt) {
      int R = mt * 16 + m;
      const char* ap = sbuf + R * 528 + k0 * 128 + q * 32;
      float4 v0 = *reinterpret_cast<const float4*>(ap);
      float4 v1 = *reinterpret_cast<const float4*>(ap + 16);
      float av[8] = {v0.x, v0.y, v0.z, v0.w, v1.x, v1.y, v1.z, v1.w};
      union { unsigned short us[8]; bf16x8 v; } uh, ul;
#pragma unroll
      for (int j = 0; j < 8; ++j) {
        unsigned int u = __float_as_uint(av[j]);
        uh.us[j] = (unsigned short)(u >> 16);
        float res = av[j] - __uint_as_float(u & 0xffff0000u);
        ul.us[j] = f2bf(res);
      }
      Ah[mt] = uh.v; Al[mt] = ul.v;
    }
#pragma unroll
    for (int mt = 0; mt < 4; ++mt)
#pragma unroll
      for (int nt = 0; nt < 2; ++nt) {
        acc[mt][nt] = __builtin_amdgcn_mfma_f32_16x16x32_bf16(Ah[mt], Bh[nt], acc[mt][nt], 0, 0, 0);
        acc[mt][nt] = __builtin_amdgcn_mfma_f32_16x16x32_bf16(Ah[mt], Bl[nt], acc[mt][nt], 0, 0, 0);
        acc[mt][nt] = __builtin_amdgcn_mfma_f32_16x16x32_bf16(Al[mt], Bh[nt], acc[mt][nt], 0, 0, 0);
      }
  }

  float avs[2], avd[2];
#pragma unroll
  for (int nt = 0; nt < 2; ++nt) {
    int c = w * 32 + nt * 16 + m;
    avs[nt] = avS[c];
    avd[nt] = avD[c];
  }
#pragma unroll
  for (int mt = 0; mt < 4; ++mt)
#pragma unroll
    for (int r = 0; r < 4; ++r) {
      float ps = acc[mt][0][r] * avs[0] + acc[mt][1][r] * avs[1];
      float pd = acc[mt][0][r] * avd[0] + acc[mt][1][r] * avd[1];
      ps += __shfl_xor(ps, 1); pd += __shfl_xor(pd, 1);
      ps += __shfl_xor(ps, 2); pd += __shfl_xor(pd, 2);
      ps += __shfl_xor(ps, 4); pd += __shfl_xor(pd, 4);
      ps += __shfl_xor(ps, 8); pd += __shfl_xor(pd, 8);
      if (m == 0) {
        int rl = mt * 16 + q * 4 + r;
        redS[rl * 4 + w] = ps;
        redD[rl * 4 + w] = pd;
      }
    }

  __syncthreads();
  unsigned short* sC = (unsigned short*)sbuf;

#pragma unroll
  for (int mt = 0; mt < 4; ++mt)
#pragma unroll
    for (int nt = 0; nt < 2; ++nt)
#pragma unroll
      for (int r = 0; r < 4; ++r) {
        int rl = mt * 16 + q * 4 + r;
        int cl = w * 32 + nt * 16 + m;
        sC[rl * 136 + cl] = f2bf(acc[mt][nt][r]);
      }
  __syncthreads();

#pragma unroll
  for (int i = 0; i < 4; ++i) {
    int idx = i * 256 + t;
    int rl = idx >> 4, kk = idx & 15;
    int gr = rbase + rl;
    if (gr < N_NODES)
      *reinterpret_cast<uint4*>(Cb + (size_t)gr * 128 + kk * 8) =
          *reinterpret_cast<const uint4*>(sC + rl * 136 + kk * 8);
  }

  if (t < 64) {
    int gr = rbase + t;
    bool ok = gr < N_NODES;
    float ps = redS[t * 4] + redS[t * 4 + 1] + redS[t * 4 + 2] + redS[t * 4 + 3];
    float pd = redD[t * 4] + redD[t * 4 + 1] + redD[t * 4 + 2] + redD[t * 4 + 3];
    if (ok) { aS[gr] = ps; aD[gr] = pd; }
    mS[t] = ok ? ps : -1e30f;
    mD[t] = ok ? pd : -1e30f;
  }
  __syncthreads();
#pragma unroll
  for (int off = 32; off > 0; off >>= 1) {
    if (t < off) { mS[t] = fmaxf(mS[t], mS[t + off]); mD[t] = fmaxf(mD[t], mD[t + off]); }
    __syncthreads();
  }
  gmax_lastblock(bid, t, redS, redD, mS, mD, slotS, slotD, gcnt, gMh);
}

// ====== FUSED: binA (blocks 0..390) + gemm1 half-1 (bid 0..781) ======
__global__ __launch_bounds__(256, 4) void k_binA_gemm1(
    const int* __restrict__ ei, int* __restrict__ bucketCnt, unsigned int* __restrict__ binned,
    const float* __restrict__ x,
    const unsigned short* __restrict__ Bhi, const unsigned short* __restrict__ Blo,
    unsigned short* __restrict__ Cb,
    const float* __restrict__ avS, const float* __restrict__ avD,
    float* __restrict__ aS, float* __restrict__ aD,
    float* __restrict__ slotS, float* __restrict__ slotD,
    int* __restrict__ gcnt, float* __restrict__ gMh) {
  __shared__ union {
    struct { int hist[NB]; int cur[NB]; } a;                       // binA: ~3.1 KB
    struct { char sbuf[64 * 528]; float redS[256]; float redD[256];
             float mS[64]; float mD[64]; } g;                      // gemm: ~36.4 KB
  } sm;
  int t = threadIdx.x;

  if (blockIdx.x < BINBLK) {
    // ---------------- binA body (R11-proven) ----------------
    for (int b = t; b < NB; b += 256) sm.a.hist[b] = 0;
    __syncthreads();
    unsigned int pk[16]; int bk[16];
#pragma unroll
    for (int j = 0; j < 16; ++j) {
      int idx = blockIdx.x * 4096 + j * 256 + t;
      if (idx < N_EDGES) {
        int s = ei[idx], d = ei[N_EDGES + idx];
        bk[j] = d >> 8;
        pk[j] = ((unsigned int)s << 8) | (unsigned int)(d & 255);
        atomicAdd(&sm.a.hist[bk[j]], 1);
      } else bk[j] = -1;
    }
    __syncthreads();
    for (int b = t; b < NB; b += 256) {
      int h = sm.a.hist[b];
      if (h) sm.a.cur[b] = b * BCAP + atomicAdd(&bucketCnt[b * 16], h);
    }
    __syncthreads();
#pragma unroll
    for (int j = 0; j < 16; ++j) {
      if (bk[j] >= 0) {
        int pos = atomicAdd(&sm.a.cur[bk[j]], 1);
        binned[pos] = pk[j];
      }
    }
    return;
  }

  gemm1_body(blockIdx.x - BINBLK, t, sm.g.sbuf, sm.g.redS, sm.g.redD, sm.g.mS, sm.g.mD,
             x, Bhi, Blo, Cb, avS, avD, aS, aD, slotS, slotD, gcnt, gMh);
}

// ====== FUSED: binB (blocks 0..390) + gemm1 half-2 (bid 782..1562) ======
__global__ __launch_bounds__(256, 4) void k_binB_gemm1(
    const unsigned int* __restrict__ binned, const int* __restrict__ binOffs,
    int* __restrict__ offs, int* __restrict__ srcs,
    const float* __restrict__ x,
    const unsigned short* __restrict__ Bhi, const unsigned short* __restrict__ Blo,
    unsigned short* __restrict__ Cb,
    const float* __restrict__ avS, const float* __restrict__ avD,
    float* __restrict__ aS, float* __restrict__ aD,
    float* __restrict__ slotS, float* __restrict__ slotD,
    int* __restrict__ gcnt, float* __restrict__ gMh) {
  __shared__ union {
    struct { int cnt[256]; int sc[256]; int cur[256]; } b;         // binB: 3 KB
    struct { char sbuf[64 * 528]; float redS[256]; float redD[256];
             float mS[64]; float mD[64]; } g;                      // gemm: ~36.4 KB
  } sm;
  int t = threadIdx.x;

  if (blockIdx.x < BINBLK) {
    // ---------------- binB body (R11-proven) ----------------
    int b = blockIdx.x;
    int node0 = b << 8;
    int nNodes = min(256, N_NODES - node0);
    int cntE = binOffs[b + 1] - binOffs[b];
    int e0 = b * BCAP, e1 = e0 + cntE;
    int base = binOffs[b] + node0;   // prior real edges + prior self-loops

    sm.b.cnt[t] = 0; __syncthreads();
    for (int i = e0 + t; i < e1; i += 256) atomicAdd(&sm.b.cnt[binned[i] & 255u], 1);
    __syncthreads();

    int v = (t < nNodes) ? sm.b.cnt[t] + 1 : 0;   // +1 self-loop
    sm.b.sc[t] = v; __syncthreads();
    for (int off = 1; off < 256; off <<= 1) {
      int x2 = (t >= off) ? sm.b.sc[t - off] : 0;
      __syncthreads();
      sm.b.sc[t] += x2;
      __syncthreads();
    }
    int excl = sm.b.sc[t] - v;
    if (t < nNodes) {
      offs[node0 + t] = base + excl;
      srcs[base + excl] = node0 + t;   // self-loop first
    }
    sm.b.cur[t] = excl + 1;
    __syncthreads();

    for (int i = e0 + t; i < e1; i += 256) {
      unsigned int e = binned[i];
      int j = (int)(e & 255u);
      int s = (int)(e >> 8);
      int p = atomicAdd(&sm.b.cur[j], 1);
      srcs[base + p] = s;
    }
    if (b == 0 && t == 0) offs[N_NODES] = TOTE;
    return;
  }

  gemm1_body(G1H1 + (blockIdx.x - BINBLK), t, sm.g.sbuf, sm.g.redS, sm.g.redD, sm.g.mS, sm.g.mD,
             x, Bhi, Blo, Cb, avS, avD, aS, aD, slotS, slotD, gcnt, gMh);
}

// exclusive scan of final bucket counts -> binOffs
__global__ __launch_bounds__(512) void k_bin_scan(const int* __restrict__ bucketCnt,
                                                  int* __restrict__ binOffs) {
  __shared__ int sc[512];
  int t = threadIdx.x;
  int v = (t < NB) ? bucketCnt[t * 16] : 0;
  sc[t] = v; __syncthreads();
  for (int off = 1; off < 512; off <<= 1) {
    int x = (t >= off) ? sc[t - off] : 0;
    __syncthreads();
    sc[t] += x;
    __syncthreads();
  }
  int excl = sc[t] - v;
  if (t <= NB) binOffs[t] = excl;
}

// ====== MFMA GEMM (layer 2 standalone), 64-row tiles, LDS-staged A (R8-proven) ======
// Last-block epilogue reduces slots -> gMh (k_gmax eliminated).
template <bool SPLIT>
__global__ __launch_bounds__(256, 4) void k_gemm_mfma(const void* __restrict__ Aptr,
                                                   const unsigned short* __restrict__ Bhi,
                                                   const unsigned short* __restrict__ Blo,
                                                   unsigned short* __restrict__ Cb,
                                                   const float* __restrict__ avS, const float* __restrict__ avD,
                                                   float* __restrict__ aS, float* __restrict__ aD,
                                                   float* __restrict__ slotS, float* __restrict__ slotD,
                                                   int* __restrict__ gcnt, float* __restrict__ gMh) {
  constexpr int SRCB  = SPLIT ? 512 : 256;        // bytes per A row in global
  constexpr int ROWB  = SPLIT ? 528 : 272;        // padded LDS row bytes
  constexpr int ABYTES = 64 * ROWB;               // 33792 / 17408 (>= 17408 sC bytes)
  constexpr int CHUNKS = ABYTES / 1024;           // 33 / 17 (1 KB per wave-instr)
  __shared__ char sbuf[ABYTES];                   // A tile, later aliased by sC
  __shared__ float redS[64 * 4], redD[64 * 4];
  __shared__ float mS[64], mD[64];
  int t = threadIdx.x;
  int w = t >> 6, lane = t & 63;
  int q = lane >> 4, m = lane & 15;
  int rbase = blockIdx.x * 64;
  const char* Ab = (const char*)Aptr;

  // ---- async stage A tile into LDS (linear dest, per-lane source computes row/pad) ----
  for (int c = w; c < CHUNKS; c += 4) {
    int L = c * 1024 + lane * 16;                 // LDS byte this lane fills
    int r = L / ROWB;
    int off = L - r * ROWB;
    int gr = min(rbase + r, N_NODES - 1);         // tail-block clamp (rows discarded later)
    const char* src = (off < SRCB) ? (Ab + (size_t)gr * SRCB + off) : Ab;  // pad -> dummy
    __builtin_amdgcn_global_load_lds((const __attribute__((address_space(1))) void*)src,
                                     (__attribute__((address_space(3))) void*)(sbuf + c * 1024),
                                     16, 0, 0);
  }

  floatx4 acc[4][2];
#pragma unroll
  for (int mt = 0; mt < 4; ++mt)
#pragma unroll
    for (int nt = 0; nt < 2; ++nt) acc[mt][nt] = (floatx4){0.f, 0.f, 0.f, 0.f};

  __syncthreads();   // staging complete (compiler drains vmcnt before s_barrier)

#pragma unroll
  for (int k0 = 0; k0 < 4; ++k0) {
    bf16x8 Bh[2], Bl[2], Ah[4], Al[4];
#pragma unroll
    for (int nt = 0; nt < 2; ++nt) {
      int ntg = w * 2 + nt;
      size_t fo = ((size_t)(ntg * 4 + k0) * 64 + lane) * 8;
      Bh[nt] = *reinterpret_cast<const bf16x8*>(Bhi + fo);
      Bl[nt] = *reinterpret_cast<const bf16x8*>(Blo + fo);
    }
#pragma unroll
    for (int mt = 0; mt < 4; ++mt) {
      int R = mt * 16 + m;
      if constexpr (SPLIT) {
        const char* ap = sbuf + R * ROWB + k0 * 128 + q * 32;
        float4 v0 = *reinterpret_cast<const float4*>(ap);
        float4 v1 = *reinterpret_cast<const float4*>(ap + 16);
        float av[8] = {v0.x, v0.y, v0.z, v0.w, v1.x, v1.y, v1.z, v1.w};
        union { unsigned short us[8]; bf16x8 v; } uh, ul;
#pragma unroll
        for (int j = 0; j < 8; ++j) {
          unsigned int u = __float_as_uint(av[j]);
          uh.us[j] = (unsigned short)(u >> 16);
          float res = av[j] - __uint_as_float(u & 0xffff0000u);
          ul.us[j] = f2bf(res);
        }
        Ah[mt] = uh.v; Al[mt] = ul.v;
      } else {
        Ah[mt] = *reinterpret_cast<const bf16x8*>(sbuf + R * ROWB + k0 * 64 + q * 16);
      }
    }
#pragma unroll
    for (int mt = 0; mt < 4; ++mt)
#pragma unroll
      for (int nt = 0; nt < 2; ++nt) {
        acc[mt][nt] = __builtin_amdgcn_mfma_f32_16x16x32_bf16(Ah[mt], Bh[nt], acc[mt][nt], 0, 0, 0);
        acc[mt][nt] = __builtin_amdgcn_mfma_f32_16x16x32_bf16(Ah[mt], Bl[nt], acc[mt][nt], 0, 0, 0);
        if constexpr (SPLIT)
          acc[mt][nt] = __builtin_amdgcn_mfma_f32_16x16x32_bf16(Al[mt], Bh[nt], acc[mt][nt], 0, 0, 0);
      }
  }

  // ---- fused alpha dots ----
  float avs[2], avd[2];
#pragma unroll
  for (int nt = 0; nt < 2; ++nt) {
    int c = w * 32 + nt * 16 + m;
    avs[nt] = avS[c];
    avd[nt] = avD[c];
  }
#pragma unroll
  for (int mt = 0; mt < 4; ++mt)
#pragma unroll
    for (int r = 0; r < 4; ++r) {
      float ps = acc[mt][0][r] * avs[0] + acc[mt][1][r] * avs[1];
      float pd = acc[mt][0][r] * avd[0] + acc[mt][1][r] * avd[1];
      ps += __shfl_xor(ps, 1); pd += __shfl_xor(pd, 1);
      ps += __shfl_xor(ps, 2); pd += __shfl_xor(pd, 2);
      ps += __shfl_xor(ps, 4); pd += __shfl_xor(pd, 4);
      ps += __shfl_xor(ps, 8); pd += __shfl_xor(pd, 8);
      if (m == 0) {
        int rl = mt * 16 + q * 4 + r;
        redS[rl * 4 + w] = ps;
        redD[rl * 4 + w] = pd;
      }
    }

  __syncthreads();   // all LDS A reads done before sC overwrites sbuf
  unsigned short* sC = (unsigned short*)sbuf;

  // ---- C -> LDS (bf16) ----
#pragma unroll
  for (int mt = 0; mt < 4; ++mt)
#pragma unroll
    for (int nt = 0; nt < 2; ++nt)
#pragma unroll
      for (int r = 0; r < 4; ++r) {
        int rl = mt * 16 + q * 4 + r;
        int cl = w * 32 + nt * 16 + m;
        sC[rl * 136 + cl] = f2bf(acc[mt][nt][r]);
      }
  __syncthreads();

  // ---- coalesced C store ----
#pragma unroll
  for (int i = 0; i < 4; ++i) {
    int idx = i * 256 + t;
    int rl = idx >> 4, kk = idx & 15;
    int gr = rbase + rl;
    if (gr < N_NODES)
      *reinterpret_cast<uint4*>(Cb + (size_t)gr * 128 + kk * 8) =
          *reinterpret_cast<const uint4*>(sC + rl * 136 + kk * 8);
  }

  // ---- alpha combine + block max ----
  if (t < 64) {
    int gr = rbase + t;
    bool ok = gr < N_NODES;
    float ps = redS[t * 4] + redS[t * 4 + 1] + redS[t * 4 + 2] + redS[t * 4 + 3];
    float pd = redD[t * 4] + redD[t * 4 + 1] + redD[t * 4 + 2] + redD[t * 4 + 3];
    if (ok) { aS[gr] = ps; aD[gr] = pd; }
    mS[t] = ok ? ps : -1e30f;
    mD[t] = ok ? pd : -1e30f;
  }
  __syncthreads();
#pragma unroll
  for (int off = 32; off > 0; off >>= 1) {
    if (t < off) { mS[t] = fmaxf(mS[t], mS[t + off]); mD[t] = fmaxf(mD[t], mD[t + off]); }
    __syncthreads();
  }
  gmax_lastblock(blockIdx.x, t, redS, redD, mS, mD, slotS, slotD, gcnt, gMh);
}

// ============ single-pass softmax + aggregation (R8-proven, byte-identical) ============
#define FMA8(E, R)                                     \
  do {                                                 \
    acc[0] += (E) * bf_lo((R).x); acc[1] += (E) * bf_hi((R).x); \
    acc[2] += (E) * bf_lo((R).y); acc[3] += (E) * bf_hi((R).y); \
    acc[4] += (E) * bf_lo((R).z); acc[5] += (E) * bf_hi((R).z); \
    acc[6] += (E) * bf_lo((R).w); acc[7] += (E) * bf_hi((R).w); \
  } while (0)

// read 4 pairs (LDS broadcast) + issue 4 row gathers into named regs
#define LDG(R0, R1, R2, R3, E0, E1, E2, E3, J)                                                   \
  do {                                                                                           \
    float2 q0 = pairs[pbase + (J) + 0];                                                          \
    float2 q1 = pairs[pbase + (J) + 1];                                                          \
    float2 q2 = pairs[pbase + (J) + 2];                                                          \
    float2 q3 = pairs[pbase + (J) + 3];                                                          \
    E0 = q0.x; E1 = q1.x; E2 = q2.x; E3 = q3.x;                                                  \
    R0 = *reinterpret_cast<const uint4*>(hbl + ((size_t)(unsigned)__float_as_int(q0.y) << 7));   \
    R1 = *reinterpret_cast<const uint4*>(hbl + ((size_t)(unsigned)__float_as_int(q1.y) << 7));   \
    R2 = *reinterpret_cast<const uint4*>(hbl + ((size_t)(unsigned)__float_as_int(q2.y) << 7));   \
    R3 = *reinterpret_cast<const uint4*>(hbl + ((size_t)(unsigned)__float_as_int(q3.y) << 7));   \
  } while (0)
#define FMAG(R0, R1, R2, R3, E0, E1, E2, E3) \
  do { FMA8(E0, R0); FMA8(E1, R1); FMA8(E2, R2); FMA8(E3, R3); } while (0)

template <bool FINAL>
__global__ __launch_bounds__(256) void k_aggregate(const unsigned short* __restrict__ hb,
                                                   const float* __restrict__ aS,
                                                   const float* __restrict__ aD,
                                                   const int* __restrict__ offs,
                                                   const int* __restrict__ srcs,
                                                   const float* __restrict__ bias,
                                                   const float* __restrict__ gMh,
                                                   unsigned short* __restrict__ outb,
                                                   const float* __restrict__ Wl,
                                                   const float* __restrict__ bl,
                                                   float* __restrict__ out) {
  __shared__ float2 pairs[16 * 17];
  __shared__ float sWt[FINAL ? 10 * 144 : 1];
  __shared__ float sbl[FINAL ? 16 : 1];
  int t = threadIdx.x;
  if constexpr (FINAL) {
    if (t < 128) {
      int jj = t >> 5, ii = t & 31;
#pragma unroll
      for (int c = 0; c < 10; ++c) sWt[c * 144 + jj * 36 + ii] = Wl[t * 10 + c];
    }
    if (t < 10) sbl[t] = bl[t];
    __syncthreads();
  }
  int g = t >> 4;
  int l = t & 15;
  int dst = blockIdx.x * 16 + g;   // N_NODES == 16*6250 exactly
  float Mh = gMh[0];
  int beg = offs[dst], end = offs[dst + 1];
  float adn = aD[dst];
  float denom = 0.f;
  float acc[8];
#pragma unroll
  for (int k = 0; k < 8; ++k) acc[k] = 0.f;
  const int pbase = g * 17;
  const unsigned short* hbl = hb + l * 8;

  uint4 ra0, ra1, ra2, ra3, rb0, rb1, rb2, rb3;
  float ea0, ea1, ea2, ea3, eb0, eb1, eb2, eb3;

  for (int chunk = beg; chunk < end; chunk += 16) {
    int i = chunk + l;
    float ex = 0.f; int s = 0;
    if (i < end) {
      s = srcs[i];
      float e = aS[s] + adn;
      e = (e > 0.f) ? e : NEG * e;
      ex = __expf(e - Mh);   // Mh >= e always
    }
    denom += ex;
    pairs[pbase + l] = make_float2(ex, __int_as_float(s));
    // same-wave LDS RAW: DS ops complete in order per wave; no barrier needed.
    // pairs are padded (ex=0, s=0) beyond cnt -> full 4-groups always safe.
    int cnt = end - chunk; if (cnt > 16) cnt = 16;
    LDG(ra0, ra1, ra2, ra3, ea0, ea1, ea2, ea3, 0);
    int j = 0;
    for (;;) {
      bool more = (j + 4) < cnt;
      if (more) LDG(rb0, rb1, rb2, rb3, eb0, eb1, eb2, eb3, j + 4);
      FMAG(ra0, ra1, ra2, ra3, ea0, ea1, ea2, ea3);
      j += 4;
      if (!more) break;
      bool more2 = (j + 4) < cnt;
      if (more2) LDG(ra0, ra1, ra2, ra3, ea0, ea1, ea2, ea3, j + 4);
      FMAG(rb0, rb1, rb2, rb3, eb0, eb1, eb2, eb3);
      j += 4;
      if (!more2) break;
    }
  }

  denom += __shfl_xor(denom, 1);
  denom += __shfl_xor(denom, 2);
  denom += __shfl_xor(denom, 4);
  denom += __shfl_xor(denom, 8);
  float inv = 1.f / (denom + 1e-16f);
  float4 b0 = *reinterpret_cast<const float4*>(bias + l * 8);
  float4 b1 = *reinterpret_cast<const float4*>(bias + l * 8 + 4);
  float o0 = fmaxf(acc[0] * inv + b0.x, 0.f), o1 = fmaxf(acc[1] * inv + b0.y, 0.f);
  float o2 = fmaxf(acc[2] * inv + b0.z, 0.f), o3 = fmaxf(acc[3] * inv + b0.w, 0.f);
  float o4 = fmaxf(acc[4] * inv + b1.x, 0.f), o5 = fmaxf(acc[5] * inv + b1.y, 0.f);
  float o6 = fmaxf(acc[6] * inv + b1.z, 0.f), o7 = fmaxf(acc[7] * inv + b1.w, 0.f);

  if constexpr (!FINAL) {
    union { unsigned short us[8]; uint4 u4; } oo;
    oo.us[0] = f2bf(o0); oo.us[1] = f2bf(o1); oo.us[2] = f2bf(o2); oo.us[3] = f2bf(o3);
    oo.us[4] = f2bf(o4); oo.us[5] = f2bf(o5); oo.us[6] = f2bf(o6); oo.us[7] = f2bf(o7);
    *reinterpret_cast<uint4*>(outb + (size_t)dst * 128 + l * 8) = oo.u4;
  } else {
    // fused classifier: feature f = l*8+k; W[f*10+c] at sWt[c*144 + (l>>2)*36 + (l&3)*8 + k]
    float p[10];
#pragma unroll
    for (int c = 0; c < 10; ++c) {
      const float4* wp = reinterpret_cast<const float4*>(&sWt[c * 144 + (l >> 2) * 36 + (l & 3) * 8]);
      float4 w0 = wp[0], w1 = wp[1];
      p[c] = o0 * w0.x + o1 * w0.y + o2 * w0.z + o3 * w0.w +
             o4 * w1.x + o5 * w1.y + o6 * w1.z + o7 * w1.w;
    }
#pragma unroll
    for (int c = 0; c < 10; ++c) {
      p[c] += __shfl_xor(p[c], 1);
      p[c] += __shfl_xor(p[c], 2);
      p[c] += __shfl_xor(p[c], 4);
      p[c] += __shfl_xor(p[c], 8);
    }
    if (l == 0) {
      float* orow = out + (size_t)dst * 10;
      *reinterpret_cast<float2*>(orow + 0) = make_float2(p[0] + sbl[0], p[1] + sbl[1]);
      *reinterpret_cast<float2*>(orow + 2) = make_float2(p[2] + sbl[2], p[3] + sbl[3]);
      *reinterpret_cast<float2*>(orow + 4) = make_float2(p[4] + sbl[4], p[5] + sbl[5]);
      *reinterpret_cast<float2*>(orow + 6) = make_float2(p[6] + sbl[6], p[7] + sbl[7]);
      *reinterpret_cast<float2*>(orow + 8) = make_float2(p[8] + sbl[8], p[9] + sbl[9]);
    }
  }
}

// ====================== launch ======================
extern "C" void kernel_launch(void* const* d_in, const int* in_sizes, int n_in,
                              void* d_out, int out_size, void* d_ws, size_t ws_size,
                              hipStream_t stream) {
  const float* x   = (const float*)d_in[0];
  const int*   ei  = (const int*)d_in[1];
  const float* W1  = (const float*)d_in[3];
  const float* as1 = (const float*)d_in[4];
  const float* ad1 = (const float*)d_in[5];
  const float* b1  = (const float*)d_in[6];
  const float* W2  = (const float*)d_in[7];
  const float* as2 = (const float*)d_in[8];
  const float* ad2 = (const float*)d_in[9];
  const float* b2  = (const float*)d_in[10];
  const float* Wl  = (const float*)d_in[11];
  const float* bl  = (const float*)d_in[12];
  float* out = (float*)d_out;

  char* p = (char*)d_ws;
  unsigned short* hb   = (unsigned short*)p; p += (size_t)N_NODES * 128 * sizeof(unsigned short);
  unsigned short* hagg = (unsigned short*)p; p += (size_t)N_NODES * 128 * sizeof(unsigned short);
  float* aS    = (float*)p; p += (size_t)N_NODES * sizeof(float);
  float* aD    = (float*)p; p += (size_t)N_NODES * sizeof(float);
  int* offs    = (int*)p;   p += (size_t)(N_NODES + 4) * sizeof(int);
  int* srcs    = (int*)p;   p += (size_t)TOTE * sizeof(int);
  int* bucketCnt = (int*)p; p += (size_t)NB * 16 * sizeof(int);
  int* binOffs   = (int*)p; p += (size_t)(NB + 4) * sizeof(int);
  float* slotS = (float*)p; p += 2048 * sizeof(float);   // 1563 gemm blocks
  float* slotD = (float*)p; p += 2048 * sizeof(float);
  float* gMh = (float*)p;   p += 4 * sizeof(float);
  int* gcnt  = (int*)p;     p += 4 * sizeof(int);        // [0]=layer1 done-count, [1]=layer2
  unsigned short* B1hi = (unsigned short*)p; p += 128 * 128 * sizeof(unsigned short);
  unsigned short* B1lo = (unsigned short*)p; p += 128 * 128 * sizeof(unsigned short);
  unsigned short* B2hi = (unsigned short*)p; p += 128 * 128 * sizeof(unsigned short);
  unsigned short* B2lo = (unsigned short*)p; p += 128 * 128 * sizeof(unsigned short);
  // binned bucket array (NB*BCAP uints = 8 MB) aliases hagg (25.6MB), dead until layer-1 agg
  unsigned int* binned = (unsigned int*)hagg;

  int gemmBlocks = GEMMN;                   // 1563
  int aggBlocks  = N_NODES / 16;            // 6250

  k_wprep<<<17, 256, 0, stream>>>(W1, W2, B1hi, B1lo, B2hi, B2lo, bucketCnt, gcnt);
  // binA overlapped with gemm1 half-1
  k_binA_gemm1<<<BINBLK + G1H1, 256, 0, stream>>>(ei, bucketCnt, binned,
                                                  x, B1hi, B1lo, hb, as1, ad1,
                                                  aS, aD, slotS, slotD, gcnt, gMh);
  k_bin_scan<<<1, 512, 0, stream>>>(bucketCnt, binOffs);
  // binB overlapped with gemm1 half-2; last gemm block reduces slots -> gMh
  k_binB_gemm1<<<BINBLK + G1H2, 256, 0, stream>>>(binned, binOffs, offs, srcs,
                                                  x, B1hi, B1lo, hb, as1, ad1,
                                                  aS, aD, slotS, slotD, gcnt, gMh);
  k_aggregate<false><<<aggBlocks, 256, 0, stream>>>(hb, aS, aD, offs, srcs, b1, gMh, hagg,
                                                    nullptr, nullptr, nullptr);
  // layer 2 (last block reduces slots -> gMh)
  k_gemm_mfma<false><<<gemmBlocks, 256, 0, stream>>>(hagg, B2hi, B2lo, hb, as2, ad2, aS, aD,
                                                     slotS, slotD, gcnt + 1, gMh);
  // fused aggregate + classifier writes out directly (k_linear eliminated)
  k_aggregate<true><<<aggBlocks, 256, 0, stream>>>(hb, aS, aD, offs, srcs, b2, gMh, hagg,
                                                   Wl, bl, out);
}

// Round 14
// 325.073 us; speedup vs baseline: 1.3779x; 1.3779x over previous
//
#include <hip/hip_runtime.h>

#define N_NODES 100000
#define N_EDGES 1600000
#define TOTE    (N_EDGES + N_NODES)
#define NEG     0.2f
#define NB      ((N_NODES + 255) >> 8)   // 391 buckets of 256 nodes
#define BCAP    5120                     // bucket capacity (mean 4096 + 16 sigma)
#define BINBLK  391                      // binA blocks (fused kernel prefix)

typedef __attribute__((ext_vector_type(8))) short bf16x8;
typedef __attribute__((ext_vector_type(4))) float floatx4;

// bf16 helpers (RTNE)
__device__ __forceinline__ unsigned short f2bf(float f) {
  unsigned int u = __float_as_uint(f);
  u += 0x7fffu + ((u >> 16) & 1u);
  return (unsigned short)(u >> 16);
}
__device__ __forceinline__ float bf_lo(unsigned int r) { return __uint_as_float(r << 16); }
__device__ __forceinline__ float bf_hi(unsigned int r) { return __uint_as_float(r & 0xffff0000u); }

// ====== W prep (blocks 0..15) + bucket counter zeroing (block 16) ======
__global__ __launch_bounds__(256) void k_wprep(const float* __restrict__ W1, const float* __restrict__ W2,
                                               unsigned short* __restrict__ B1hi, unsigned short* __restrict__ B1lo,
                                               unsigned short* __restrict__ B2hi, unsigned short* __restrict__ B2lo,
                                               int* __restrict__ bucketCnt) {
  int b = blockIdx.x;                       // 0..16
  int t = threadIdx.x;
  if (b == 16) {
    for (int i = t; i < NB * 16; i += 256) bucketCnt[i] = 0;
    return;
  }
  const float* W = (b < 8) ? W1 : W2;
  unsigned short* Bh = (b < 8) ? B1hi : B2hi;
  unsigned short* Bl = (b < 8) ? B1lo : B2lo;
  int ntile = b & 7;
  int kq = t >> 6, lane = t & 63;
  int q = lane >> 4, m = lane & 15;
  int n = ntile * 16 + m;
  union { unsigned short us[8]; uint4 u4; } hi, lo;
#pragma unroll
  for (int j = 0; j < 8; ++j) {
    int k = kq * 32 + q * 8 + j;
    float w = W[(size_t)k * 128 + n];
    unsigned int u = __float_as_uint(w);
    hi.us[j] = (unsigned short)(u >> 16);                 // truncation hi
    float res = w - __uint_as_float(u & 0xffff0000u);     // exact residual
    lo.us[j] = f2bf(res);
  }
  size_t fo = ((size_t)(ntile * 4 + kq) * 64 + lane) * 8;
  *reinterpret_cast<uint4*>(Bh + fo) = hi.u4;
  *reinterpret_cast<uint4*>(Bl + fo) = lo.u4;
}

// ====== FUSED: binA (blocks 0..390) + layer-1 GEMM (blocks 391..1953) ======
// The two halves are data-independent (binA: ei only; gemm1: x + wprep output),
// so packing them in one dispatch overlaps binA's scatter-latency with gemm's
// throughput work. LDS overlaid via union (36.4 KB = gemm size, 4 blocks/CU).
__global__ __launch_bounds__(256, 4) void k_binA_gemm1(
    const int* __restrict__ ei, int* __restrict__ bucketCnt, unsigned int* __restrict__ binned,
    const float* __restrict__ x,
    const unsigned short* __restrict__ Bhi, const unsigned short* __restrict__ Blo,
    unsigned short* __restrict__ Cb,
    const float* __restrict__ avS, const float* __restrict__ avD,
    float* __restrict__ aS, float* __restrict__ aD,
    float* __restrict__ slotS, float* __restrict__ slotD) {
  __shared__ union {
    struct { int hist[NB]; int cur[NB]; } a;                       // binA: ~3.1 KB
    struct { char sbuf[64 * 528]; float redS[256]; float redD[256];
             float mS[64]; float mD[64]; } g;                      // gemm: ~36.4 KB
  } sm;
  int t = threadIdx.x;

  if (blockIdx.x < BINBLK) {
    // ---------------- binA body (unchanged from R8) ----------------
    for (int b = t; b < NB; b += 256) sm.a.hist[b] = 0;
    __syncthreads();
    unsigned int pk[16]; int bk[16];
#pragma unroll
    for (int j = 0; j < 16; ++j) {
      int idx = blockIdx.x * 4096 + j * 256 + t;
      if (idx < N_EDGES) {
        int s = ei[idx], d = ei[N_EDGES + idx];
        bk[j] = d >> 8;
        pk[j] = ((unsigned int)s << 8) | (unsigned int)(d & 255);
        atomicAdd(&sm.a.hist[bk[j]], 1);
      } else bk[j] = -1;
    }
    __syncthreads();
    for (int b = t; b < NB; b += 256) {
      int h = sm.a.hist[b];
      if (h) sm.a.cur[b] = b * BCAP + atomicAdd(&bucketCnt[b * 16], h);
    }
    __syncthreads();
#pragma unroll
    for (int j = 0; j < 16; ++j) {
      if (bk[j] >= 0) {
        int pos = atomicAdd(&sm.a.cur[bk[j]], 1);
        binned[pos] = pk[j];
      }
    }
    return;
  }

  // ---------------- gemm1 body (R8 SPLIT=true, LDS-staged) ----------------
  int bid = blockIdx.x - BINBLK;
  int w = t >> 6, lane = t & 63;
  int q = lane >> 4, m = lane & 15;
  int rbase = bid * 64;
  const char* Ab = (const char*)x;

  // async stage A tile into LDS (fp32 rows 512B -> padded 528B; 33 KB chunks)
  for (int c = w; c < 33; c += 4) {
    int L = c * 1024 + lane * 16;
    int r = L / 528;
    int off = L - r * 528;
    int gr = min(rbase + r, N_NODES - 1);
    const char* src = (off < 512) ? (Ab + (size_t)gr * 512 + off) : Ab;
    __builtin_amdgcn_global_load_lds((const __attribute__((address_space(1))) void*)src,
                                     (__attribute__((address_space(3))) void*)(sm.g.sbuf + c * 1024),
                                     16, 0, 0);
  }

  floatx4 acc[4][2];
#pragma unroll
  for (int mt = 0; mt < 4; ++mt)
#pragma unroll
    for (int nt = 0; nt < 2; ++nt) acc[mt][nt] = (floatx4){0.f, 0.f, 0.f, 0.f};

  __syncthreads();

#pragma unroll
  for (int k0 = 0; k0 < 4; ++k0) {
    bf16x8 Bh[2], Bl[2], Ah[4], Al[4];
#pragma unroll
    for (int nt = 0; nt < 2; ++nt) {
      int ntg = w * 2 + nt;
      size_t fo = ((size_t)(ntg * 4 + k0) * 64 + lane) * 8;
      Bh[nt] = *reinterpret_cast<const bf16x8*>(Bhi + fo);
      Bl[nt] = *reinterpret_cast<const bf16x8*>(Blo + fo);
    }
#pragma unroll
    for (int mt = 0; mt < 4; ++mt) {
      int R = mt * 16 + m;
      const char* ap = sm.g.sbuf + R * 528 + k0 * 128 + q * 32;
      float4 v0 = *reinterpret_cast<const float4*>(ap);
      float4 v1 = *reinterpret_cast<const float4*>(ap + 16);
      float av[8] = {v0.x, v0.y, v0.z, v0.w, v1.x, v1.y, v1.z, v1.w};
      union { unsigned short us[8]; bf16x8 v; } uh, ul;
#pragma unroll
      for (int j = 0; j < 8; ++j) {
        unsigned int u = __float_as_uint(av[j]);
        uh.us[j] = (unsigned short)(u >> 16);
        float res = av[j] - __uint_as_float(u & 0xffff0000u);
        ul.us[j] = f2bf(res);
      }
      Ah[mt] = uh.v; Al[mt] = ul.v;
    }
#pragma unroll
    for (int mt = 0; mt < 4; ++mt)
#pragma unroll
      for (int nt = 0; nt < 2; ++nt) {
        acc[mt][nt] = __builtin_amdgcn_mfma_f32_16x16x32_bf16(Ah[mt], Bh[nt], acc[mt][nt], 0, 0, 0);
        acc[mt][nt] = __builtin_amdgcn_mfma_f32_16x16x32_bf16(Ah[mt], Bl[nt], acc[mt][nt], 0, 0, 0);
        acc[mt][nt] = __builtin_amdgcn_mfma_f32_16x16x32_bf16(Al[mt], Bh[nt], acc[mt][nt], 0, 0, 0);
      }
  }

  float avs[2], avd[2];
#pragma unroll
  for (int nt = 0; nt < 2; ++nt) {
    int c = w * 32 + nt * 16 + m;
    avs[nt] = avS[c];
    avd[nt] = avD[c];
  }
#pragma unroll
  for (int mt = 0; mt < 4; ++mt)
#pragma unroll
    for (int r = 0; r < 4; ++r) {
      float ps = acc[mt][0][r] * avs[0] + acc[mt][1][r] * avs[1];
      float pd = acc[mt][0][r] * avd[0] + acc[mt][1][r] * avd[1];
      ps += __shfl_xor(ps, 1); pd += __shfl_xor(pd, 1);
      ps += __shfl_xor(ps, 2); pd += __shfl_xor(pd, 2);
      ps += __shfl_xor(ps, 4); pd += __shfl_xor(pd, 4);
      ps += __shfl_xor(ps, 8); pd += __shfl_xor(pd, 8);
      if (m == 0) {
        int rl = mt * 16 + q * 4 + r;
        sm.g.redS[rl * 4 + w] = ps;
        sm.g.redD[rl * 4 + w] = pd;
      }
    }

  __syncthreads();
  unsigned short* sC = (unsigned short*)sm.g.sbuf;

#pragma unroll
  for (int mt = 0; mt < 4; ++mt)
#pragma unroll
    for (int nt = 0; nt < 2; ++nt)
#pragma unroll
      for (int r = 0; r < 4; ++r) {
        int rl = mt * 16 + q * 4 + r;
        int cl = w * 32 + nt * 16 + m;
        sC[rl * 136 + cl] = f2bf(acc[mt][nt][r]);
      }
  __syncthreads();

#pragma unroll
  for (int i = 0; i < 4; ++i) {
    int idx = i * 256 + t;
    int rl = idx >> 4, kk = idx & 15;
    int gr = rbase + rl;
    if (gr < N_NODES)
      *reinterpret_cast<uint4*>(Cb + (size_t)gr * 128 + kk * 8) =
          *reinterpret_cast<const uint4*>(sC + rl * 136 + kk * 8);
  }

  if (t < 64) {
    int gr = rbase + t;
    bool ok = gr < N_NODES;
    float ps = sm.g.redS[t * 4] + sm.g.redS[t * 4 + 1] + sm.g.redS[t * 4 + 2] + sm.g.redS[t * 4 + 3];
    float pd = sm.g.redD[t * 4] + sm.g.redD[t * 4 + 1] + sm.g.redD[t * 4 + 2] + sm.g.redD[t * 4 + 3];
    if (ok) { aS[gr] = ps; aD[gr] = pd; }
    sm.g.mS[t] = ok ? ps : -1e30f;
    sm.g.mD[t] = ok ? pd : -1e30f;
  }
  __syncthreads();
#pragma unroll
  for (int off = 32; off > 0; off >>= 1) {
    if (t < off) {
      sm.g.mS[t] = fmaxf(sm.g.mS[t], sm.g.mS[t + off]);
      sm.g.mD[t] = fmaxf(sm.g.mD[t], sm.g.mD[t + off]);
    }
    __syncthreads();
  }
  if (t == 0) { slotS[bid] = sm.g.mS[0]; slotD[bid] = sm.g.mD[0]; }
}

// exclusive scan of final bucket counts -> binOffs
__global__ __launch_bounds__(512) void k_bin_scan(const int* __restrict__ bucketCnt,
                                                  int* __restrict__ binOffs) {
  __shared__ int sc[512];
  int t = threadIdx.x;
  int v = (t < NB) ? bucketCnt[t * 16] : 0;
  sc[t] = v; __syncthreads();
  for (int off = 1; off < 512; off <<= 1) {
    int x = (t >= off) ? sc[t - off] : 0;
    __syncthreads();
    sc[t] += x;
    __syncthreads();
  }
  int excl = sc[t] - v;
  if (t <= NB) binOffs[t] = excl;
}

// pass B: per-bucket exact CSR (offs + srcs)
__global__ __launch_bounds__(256) void k_binB(const unsigned int* __restrict__ binned,
                                              const int* __restrict__ binOffs,
                                              int* __restrict__ offs, int* __restrict__ srcs) {
  __shared__ int cnt[256];
  __shared__ int sc[256];
  __shared__ int cur[256];
  int b = blockIdx.x;
  int t = threadIdx.x;
  int node0 = b << 8;
  int nNodes = min(256, N_NODES - node0);
  int cntE = binOffs[b + 1] - binOffs[b];
  int e0 = b * BCAP, e1 = e0 + cntE;
  int base = binOffs[b] + node0;   // prior real edges + prior self-loops

  cnt[t] = 0; __syncthreads();
  for (int i = e0 + t; i < e1; i += 256) atomicAdd(&cnt[binned[i] & 255u], 1);
  __syncthreads();

  int v = (t < nNodes) ? cnt[t] + 1 : 0;   // +1 self-loop
  sc[t] = v; __syncthreads();
  for (int off = 1; off < 256; off <<= 1) {
    int x = (t >= off) ? sc[t - off] : 0;
    __syncthreads();
    sc[t] += x;
    __syncthreads();
  }
  int excl = sc[t] - v;
  if (t < nNodes) {
    offs[node0 + t] = base + excl;
    srcs[base + excl] = node0 + t;   // self-loop first
  }
  cur[t] = excl + 1;
  __syncthreads();

  for (int i = e0 + t; i < e1; i += 256) {
    unsigned int e = binned[i];
    int j = (int)(e & 255u);
    int s = (int)(e >> 8);
    int p = atomicAdd(&cur[j], 1);
    srcs[base + p] = s;
  }
  if (b == 0 && t == 0) offs[N_NODES] = TOTE;
}

// ====== MFMA GEMM (layer 2 standalone), 64-row tiles, LDS-staged A (R8-proven) ======
template <bool SPLIT>
__global__ __launch_bounds__(256, 4) void k_gemm_mfma(const void* __restrict__ Aptr,
                                                   const unsigned short* __restrict__ Bhi,
                                                   const unsigned short* __restrict__ Blo,
                                                   unsigned short* __restrict__ Cb,
                                                   const float* __restrict__ avS, const float* __restrict__ avD,
                                                   float* __restrict__ aS, float* __restrict__ aD,
                                                   float* __restrict__ slotS, float* __restrict__ slotD) {
  constexpr int SRCB  = SPLIT ? 512 : 256;        // bytes per A row in global
  constexpr int ROWB  = SPLIT ? 528 : 272;        // padded LDS row bytes
  constexpr int ABYTES = 64 * ROWB;               // 33792 / 17408 (>= 17408 sC bytes)
  constexpr int CHUNKS = ABYTES / 1024;           // 33 / 17 (1 KB per wave-instr)
  __shared__ char sbuf[ABYTES];                   // A tile, later aliased by sC
  __shared__ float redS[64 * 4], redD[64 * 4];
  __shared__ float mS[64], mD[64];
  int t = threadIdx.x;
  int w = t >> 6, lane = t & 63;
  int q = lane >> 4, m = lane & 15;
  int rbase = blockIdx.x * 64;
  const char* Ab = (const char*)Aptr;

  // ---- async stage A tile into LDS (linear dest, per-lane source computes row/pad) ----
  for (int c = w; c < CHUNKS; c += 4) {
    int L = c * 1024 + lane * 16;                 // LDS byte this lane fills
    int r = L / ROWB;
    int off = L - r * ROWB;
    int gr = min(rbase + r, N_NODES - 1);         // tail-block clamp (rows discarded later)
    const char* src = (off < SRCB) ? (Ab + (size_t)gr * SRCB + off) : Ab;  // pad -> dummy
    __builtin_amdgcn_global_load_lds((const __attribute__((address_space(1))) void*)src,
                                     (__attribute__((address_space(3))) void*)(sbuf + c * 1024),
                                     16, 0, 0);
  }

  floatx4 acc[4][2];
#pragma unroll
  for (int mt = 0; mt < 4; ++mt)
#pragma unroll
    for (int nt = 0; nt < 2; ++nt) acc[mt][nt] = (floatx4){0.f, 0.f, 0.f, 0.f};

  __syncthreads();   // staging complete (compiler drains vmcnt before s_barrier)

#pragma unroll
  for (int k0 = 0; k0 < 4; ++k0) {
    bf16x8 Bh[2], Bl[2], Ah[4], Al[4];
#pragma unroll
    for (int nt = 0; nt < 2; ++nt) {
      int ntg = w * 2 + nt;
      size_t fo = ((size_t)(ntg * 4 + k0) * 64 + lane) * 8;
      Bh[nt] = *reinterpret_cast<const bf16x8*>(Bhi + fo);
      Bl[nt] = *reinterpret_cast<const bf16x8*>(Blo + fo);
    }
#pragma unroll
    for (int mt = 0; mt < 4; ++mt) {
      int R = mt * 16 + m;
      if constexpr (SPLIT) {
        const char* ap = sbuf + R * ROWB + k0 * 128 + q * 32;
        float4 v0 = *reinterpret_cast<const float4*>(ap);
        float4 v1 = *reinterpret_cast<const float4*>(ap + 16);
        float av[8] = {v0.x, v0.y, v0.z, v0.w, v1.x, v1.y, v1.z, v1.w};
        union { unsigned short us[8]; bf16x8 v; } uh, ul;
#pragma unroll
        for (int j = 0; j < 8; ++j) {
          unsigned int u = __float_as_uint(av[j]);
          uh.us[j] = (unsigned short)(u >> 16);
          float res = av[j] - __uint_as_float(u & 0xffff0000u);
          ul.us[j] = f2bf(res);
        }
        Ah[mt] = uh.v; Al[mt] = ul.v;
      } else {
        Ah[mt] = *reinterpret_cast<const bf16x8*>(sbuf + R * ROWB + k0 * 64 + q * 16);
      }
    }
#pragma unroll
    for (int mt = 0; mt < 4; ++mt)
#pragma unroll
      for (int nt = 0; nt < 2; ++nt) {
        acc[mt][nt] = __builtin_amdgcn_mfma_f32_16x16x32_bf16(Ah[mt], Bh[nt], acc[mt][nt], 0, 0, 0);
        acc[mt][nt] = __builtin_amdgcn_mfma_f32_16x16x32_bf16(Ah[mt], Bl[nt], acc[mt][nt], 0, 0, 0);
        if constexpr (SPLIT)
          acc[mt][nt] = __builtin_amdgcn_mfma_f32_16x16x32_bf16(Al[mt], Bh[nt], acc[mt][nt], 0, 0, 0);
      }
  }

  // ---- fused alpha dots ----
  float avs[2], avd[2];
#pragma unroll
  for (int nt = 0; nt < 2; ++nt) {
    int c = w * 32 + nt * 16 + m;
    avs[nt] = avS[c];
    avd[nt] = avD[c];
  }
#pragma unroll
  for (int mt = 0; mt < 4; ++mt)
#pragma unroll
    for (int r = 0; r < 4; ++r) {
      float ps = acc[mt][0][r] * avs[0] + acc[mt][1][r] * avs[1];
      float pd = acc[mt][0][r] * avd[0] + acc[mt][1][r] * avd[1];
      ps += __shfl_xor(ps, 1); pd += __shfl_xor(pd, 1);
      ps += __shfl_xor(ps, 2); pd += __shfl_xor(pd, 2);
      ps += __shfl_xor(ps, 4); pd += __shfl_xor(pd, 4);
      ps += __shfl_xor(ps, 8); pd += __shfl_xor(pd, 8);
      if (m == 0) {
        int rl = mt * 16 + q * 4 + r;
        redS[rl * 4 + w] = ps;
        redD[rl * 4 + w] = pd;
      }
    }

  __syncthreads();   // all LDS A reads done before sC overwrites sbuf
  unsigned short* sC = (unsigned short*)sbuf;

  // ---- C -> LDS (bf16) ----
#pragma unroll
  for (int mt = 0; mt < 4; ++mt)
#pragma unroll
    for (int nt = 0; nt < 2; ++nt)
#pragma unroll
      for (int r = 0; r < 4; ++r) {
        int rl = mt * 16 + q * 4 + r;
        int cl = w * 32 + nt * 16 + m;
        sC[rl * 136 + cl] = f2bf(acc[mt][nt][r]);
      }
  __syncthreads();

  // ---- coalesced C store ----
#pragma unroll
  for (int i = 0; i < 4; ++i) {
    int idx = i * 256 + t;
    int rl = idx >> 4, kk = idx & 15;
    int gr = rbase + rl;
    if (gr < N_NODES)
      *reinterpret_cast<uint4*>(Cb + (size_t)gr * 128 + kk * 8) =
          *reinterpret_cast<const uint4*>(sC + rl * 136 + kk * 8);
  }

  // ---- alpha combine + block max ----
  if (t < 64) {
    int gr = rbase + t;
    bool ok = gr < N_NODES;
    float ps = redS[t * 4] + redS[t * 4 + 1] + redS[t * 4 + 2] + redS[t * 4 + 3];
    float pd = redD[t * 4] + redD[t * 4 + 1] + redD[t * 4 + 2] + redD[t * 4 + 3];
    if (ok) { aS[gr] = ps; aD[gr] = pd; }
    mS[t] = ok ? ps : -1e30f;
    mD[t] = ok ? pd : -1e30f;
  }
  __syncthreads();
#pragma unroll
  for (int off = 32; off > 0; off >>= 1) {
    if (t < off) { mS[t] = fmaxf(mS[t], mS[t + off]); mD[t] = fmaxf(mD[t], mD[t + off]); }
    __syncthreads();
  }
  if (t == 0) { slotS[blockIdx.x] = mS[0]; slotD[blockIdx.x] = mD[0]; }
}

__global__ __launch_bounds__(256) void k_gmax(const float* __restrict__ slotS,
                                              const float* __restrict__ slotD,
                                              int n, float* __restrict__ gMh) {
  __shared__ float sS[256], sD[256];
  int t = threadIdx.x;
  float ms = -1e30f, md = -1e30f;
  for (int i = t; i < n; i += 256) { ms = fmaxf(ms, slotS[i]); md = fmaxf(md, slotD[i]); }
  sS[t] = ms; sD[t] = md;
  __syncthreads();
#pragma unroll
  for (int off = 128; off > 0; off >>= 1) {
    if (t < off) { sS[t] = fmaxf(sS[t], sS[t + off]); sD[t] = fmaxf(sD[t], sD[t + off]); }
    __syncthreads();
  }
  if (t == 0) {
    float M = sS[0] + sD[0];
    gMh[0] = (M > 0.f) ? M : NEG * M;
  }
}

// ============ single-pass softmax + aggregation (R8-proven, byte-identical) ============
#define FMA8(E, R)                                     \
  do {                                                 \
    acc[0] += (E) * bf_lo((R).x); acc[1] += (E) * bf_hi((R).x); \
    acc[2] += (E) * bf_lo((R).y); acc[3] += (E) * bf_hi((R).y); \
    acc[4] += (E) * bf_lo((R).z); acc[5] += (E) * bf_hi((R).z); \
    acc[6] += (E) * bf_lo((R).w); acc[7] += (E) * bf_hi((R).w); \
  } while (0)

// read 4 pairs (LDS broadcast) + issue 4 row gathers into named regs
#define LDG(R0, R1, R2, R3, E0, E1, E2, E3, J)                                                   \
  do {                                                                                           \
    float2 q0 = pairs[pbase + (J) + 0];                                                          \
    float2 q1 = pairs[pbase + (J) + 1];                                                          \
    float2 q2 = pairs[pbase + (J) + 2];                                                          \
    float2 q3 = pairs[pbase + (J) + 3];                                                          \
    E0 = q0.x; E1 = q1.x; E2 = q2.x; E3 = q3.x;                                                  \
    R0 = *reinterpret_cast<const uint4*>(hbl + ((size_t)(unsigned)__float_as_int(q0.y) << 7));   \
    R1 = *reinterpret_cast<const uint4*>(hbl + ((size_t)(unsigned)__float_as_int(q1.y) << 7));   \
    R2 = *reinterpret_cast<const uint4*>(hbl + ((size_t)(unsigned)__float_as_int(q2.y) << 7));   \
    R3 = *reinterpret_cast<const uint4*>(hbl + ((size_t)(unsigned)__float_as_int(q3.y) << 7));   \
  } while (0)
#define FMAG(R0, R1, R2, R3, E0, E1, E2, E3) \
  do { FMA8(E0, R0); FMA8(E1, R1); FMA8(E2, R2); FMA8(E3, R3); } while (0)

template <bool FINAL>
__global__ __launch_bounds__(256) void k_aggregate(const unsigned short* __restrict__ hb,
                                                   const float* __restrict__ aS,
                                                   const float* __restrict__ aD,
                                                   const int* __restrict__ offs,
                                                   const int* __restrict__ srcs,
                                                   const float* __restrict__ bias,
                                                   const float* __restrict__ gMh,
                                                   unsigned short* __restrict__ outb,
                                                   const float* __restrict__ Wl,
                                                   const float* __restrict__ bl,
                                                   float* __restrict__ out) {
  __shared__ float2 pairs[16 * 17];
  __shared__ float sWt[FINAL ? 10 * 144 : 1];
  __shared__ float sbl[FINAL ? 16 : 1];
  int t = threadIdx.x;
  if constexpr (FINAL) {
    if (t < 128) {
      int jj = t >> 5, ii = t & 31;
#pragma unroll
      for (int c = 0; c < 10; ++c) sWt[c * 144 + jj * 36 + ii] = Wl[t * 10 + c];
    }
    if (t < 10) sbl[t] = bl[t];
    __syncthreads();
  }
  int g = t >> 4;
  int l = t & 15;
  int dst = blockIdx.x * 16 + g;   // N_NODES == 16*6250 exactly
  float Mh = gMh[0];
  int beg = offs[dst], end = offs[dst + 1];
  float adn = aD[dst];
  float denom = 0.f;
  float acc[8];
#pragma unroll
  for (int k = 0; k < 8; ++k) acc[k] = 0.f;
  const int pbase = g * 17;
  const unsigned short* hbl = hb + l * 8;

  uint4 ra0, ra1, ra2, ra3, rb0, rb1, rb2, rb3;
  float ea0, ea1, ea2, ea3, eb0, eb1, eb2, eb3;

  for (int chunk = beg; chunk < end; chunk += 16) {
    int i = chunk + l;
    float ex = 0.f; int s = 0;
    if (i < end) {
      s = srcs[i];
      float e = aS[s] + adn;
      e = (e > 0.f) ? e : NEG * e;
      ex = __expf(e - Mh);   // Mh >= e always
    }
    denom += ex;
    pairs[pbase + l] = make_float2(ex, __int_as_float(s));
    // same-wave LDS RAW: DS ops complete in order per wave; no barrier needed.
    // pairs are padded (ex=0, s=0) beyond cnt -> full 4-groups always safe.
    int cnt = end - chunk; if (cnt > 16) cnt = 16;
    LDG(ra0, ra1, ra2, ra3, ea0, ea1, ea2, ea3, 0);
    int j = 0;
    for (;;) {
      bool more = (j + 4) < cnt;
      if (more) LDG(rb0, rb1, rb2, rb3, eb0, eb1, eb2, eb3, j + 4);
      FMAG(ra0, ra1, ra2, ra3, ea0, ea1, ea2, ea3);
      j += 4;
      if (!more) break;
      bool more2 = (j + 4) < cnt;
      if (more2) LDG(ra0, ra1, ra2, ra3, ea0, ea1, ea2, ea3, j + 4);
      FMAG(rb0, rb1, rb2, rb3, eb0, eb1, eb2, eb3);
      j += 4;
      if (!more2) break;
    }
  }

  denom += __shfl_xor(denom, 1);
  denom += __shfl_xor(denom, 2);
  denom += __shfl_xor(denom, 4);
  denom += __shfl_xor(denom, 8);
  float inv = 1.f / (denom + 1e-16f);
  float4 b0 = *reinterpret_cast<const float4*>(bias + l * 8);
  float4 b1 = *reinterpret_cast<const float4*>(bias + l * 8 + 4);
  float o0 = fmaxf(acc[0] * inv + b0.x, 0.f), o1 = fmaxf(acc[1] * inv + b0.y, 0.f);
  float o2 = fmaxf(acc[2] * inv + b0.z, 0.f), o3 = fmaxf(acc[3] * inv + b0.w, 0.f);
  float o4 = fmaxf(acc[4] * inv + b1.x, 0.f), o5 = fmaxf(acc[5] * inv + b1.y, 0.f);
  float o6 = fmaxf(acc[6] * inv + b1.z, 0.f), o7 = fmaxf(acc[7] * inv + b1.w, 0.f);

  if constexpr (!FINAL) {
    union { unsigned short us[8]; uint4 u4; } oo;
    oo.us[0] = f2bf(o0); oo.us[1] = f2bf(o1); oo.us[2] = f2bf(o2); oo.us[3] = f2bf(o3);
    oo.us[4] = f2bf(o4); oo.us[5] = f2bf(o5); oo.us[6] = f2bf(o6); oo.us[7] = f2bf(o7);
    *reinterpret_cast<uint4*>(outb + (size_t)dst * 128 + l * 8) = oo.u4;
  } else {
    // fused classifier: feature f = l*8+k; W[f*10+c] at sWt[c*144 + (l>>2)*36 + (l&3)*8 + k]
    float p[10];
#pragma unroll
    for (int c = 0; c < 10; ++c) {
      const float4* wp = reinterpret_cast<const float4*>(&sWt[c * 144 + (l >> 2) * 36 + (l & 3) * 8]);
      float4 w0 = wp[0], w1 = wp[1];
      p[c] = o0 * w0.x + o1 * w0.y + o2 * w0.z + o3 * w0.w +
             o4 * w1.x + o5 * w1.y + o6 * w1.z + o7 * w1.w;
    }
#pragma unroll
    for (int c = 0; c < 10; ++c) {
      p[c] += __shfl_xor(p[c], 1);
      p[c] += __shfl_xor(p[c], 2);
      p[c] += __shfl_xor(p[c], 4);
      p[c] += __shfl_xor(p[c], 8);
    }
    if (l == 0) {
      float* orow = out + (size_t)dst * 10;
      *reinterpret_cast<float2*>(orow + 0) = make_float2(p[0] + sbl[0], p[1] + sbl[1]);
      *reinterpret_cast<float2*>(orow + 2) = make_float2(p[2] + sbl[2], p[3] + sbl[3]);
      *reinterpret_cast<float2*>(orow + 4) = make_float2(p[4] + sbl[4], p[5] + sbl[5]);
      *reinterpret_cast<float2*>(orow + 6) = make_float2(p[6] + sbl[6], p[7] + sbl[7]);
      *reinterpret_cast<float2*>(orow + 8) = make_float2(p[8] + sbl[8], p[9] + sbl[9]);
    }
  }
}

// ====================== launch ======================
extern "C" void kernel_launch(void* const* d_in, const int* in_sizes, int n_in,
                              void* d_out, int out_size, void* d_ws, size_t ws_size,
                              hipStream_t stream) {
  const float* x   = (const float*)d_in[0];
  const int*   ei  = (const int*)d_in[1];
  const float* W1  = (const float*)d_in[3];
  const float* as1 = (const float*)d_in[4];
  const float* ad1 = (const float*)d_in[5];
  const float* b1  = (const float*)d_in[6];
  const float* W2  = (const float*)d_in[7];
  const float* as2 = (const float*)d_in[8];
  const float* ad2 = (const float*)d_in[9];
  const float* b2  = (const float*)d_in[10];
  const float* Wl  = (const float*)d_in[11];
  const float* bl  = (const float*)d_in[12];
  float* out = (float*)d_out;

  char* p = (char*)d_ws;
  unsigned short* hb   = (unsigned short*)p; p += (size_t)N_NODES * 128 * sizeof(unsigned short);
  unsigned short* hagg = (unsigned short*)p; p += (size_t)N_NODES * 128 * sizeof(unsigned short);
  float* aS    = (float*)p; p += (size_t)N_NODES * sizeof(float);
  float* aD    = (float*)p; p += (size_t)N_NODES * sizeof(float);
  int* offs    = (int*)p;   p += (size_t)(N_NODES + 4) * sizeof(int);
  int* srcs    = (int*)p;   p += (size_t)TOTE * sizeof(int);
  int* bucketCnt = (int*)p; p += (size_t)NB * 16 * sizeof(int);
  int* binOffs   = (int*)p; p += (size_t)(NB + 4) * sizeof(int);
  float* slotS = (float*)p; p += 2048 * sizeof(float);   // 1563 gemm blocks
  float* slotD = (float*)p; p += 2048 * sizeof(float);
  float* gMh = (float*)p;   p += 4 * sizeof(float);
  unsigned short* B1hi = (unsigned short*)p; p += 128 * 128 * sizeof(unsigned short);
  unsigned short* B1lo = (unsigned short*)p; p += 128 * 128 * sizeof(unsigned short);
  unsigned short* B2hi = (unsigned short*)p; p += 128 * 128 * sizeof(unsigned short);
  unsigned short* B2lo = (unsigned short*)p; p += 128 * 128 * sizeof(unsigned short);
  // binned bucket array (NB*BCAP uints = 8 MB) aliases hagg (25.6MB), dead until layer-1 agg
  unsigned int* binned = (unsigned int*)hagg;

  int gemmBlocks = (N_NODES + 63) / 64;     // 1563
  int aggBlocks  = N_NODES / 16;            // 6250

  k_wprep<<<17, 256, 0, stream>>>(W1, W2, B1hi, B1lo, B2hi, B2lo, bucketCnt);
  // fused: binA (391 blocks) overlapped with layer-1 gemm (1563 blocks)
  k_binA_gemm1<<<BINBLK + gemmBlocks, 256, 0, stream>>>(ei, bucketCnt, binned,
                                                        x, B1hi, B1lo, hb, as1, ad1,
                                                        aS, aD, slotS, slotD);
  k_bin_scan<<<1, 512, 0, stream>>>(bucketCnt, binOffs);
  k_binB<<<NB, 256, 0, stream>>>(binned, binOffs, offs, srcs);
  k_gmax<<<1, 256, 0, stream>>>(slotS, slotD, gemmBlocks, gMh);
  k_aggregate<false><<<aggBlocks, 256, 0, stream>>>(hb, aS, aD, offs, srcs, b1, gMh, hagg,
                                                    nullptr, nullptr, nullptr);
  // layer 2
  k_gemm_mfma<false><<<gemmBlocks, 256, 0, stream>>>(hagg, B2hi, B2lo, hb, as2, ad2, aS, aD, slotS, slotD);
  k_gmax<<<1, 256, 0, stream>>>(slotS, slotD, gemmBlocks, gMh);
  // fused aggregate + classifier writes out directly (k_linear eliminated)
  k_aggregate<true><<<aggBlocks, 256, 0, stream>>>(hb, aS, aD, offs, srcs, b2, gMh, hagg,
                                                   Wl, bl, out);
}